// Round 7
// baseline (397.671 us; speedup 1.0000x reference)
//
#include <hip/hip_runtime.h>
#include <math.h>

#define MAX_LEN 4096
#define D_MODEL 768
#define PE_DIM 65
#define MLP_W 64
#define NBATCH 4
#define D3 2304               // (ORDER+1)*D_MODEL
#define ROWS (NBATCH*MAX_LEN) // 16384

typedef unsigned short u16;
typedef unsigned int u32;
typedef float f4 __attribute__((ext_vector_type(4)));
typedef __bf16 bf16x8 __attribute__((ext_vector_type(8)));
typedef float f32x4 __attribute__((ext_vector_type(4)));

__device__ inline u16 f2bf(float x) {
    u32 u = __float_as_uint(x);
    u += 0x7fffu + ((u >> 16) & 1u);   // round-to-nearest-even
    return (u16)(u >> 16);
}
__device__ inline float bf2f(u16 v) { return __uint_as_float((u32)v << 16); }
__device__ inline u32 pk2(float a, float b) {
    return (u32)f2bf(a) | ((u32)f2bf(b) << 16);
}

// direct global->LDS async copy, 16B per lane; lds base must be wave-uniform.
// One call moves 64 lanes x 16B = 1KB, landing at ldsbase + lane*16B.
#define GLDS16(gp, lp) __builtin_amdgcn_global_load_lds( \
    (const __attribute__((address_space(1))) u32*)(gp), \
    (__attribute__((address_space(3))) u32*)(lp), 16, 0, 0)

// ---------------------------------------------------------------------------
// K1a: 3-layer sin-MLP -> k3 (MAX_LEN x 64 fp32).
// ---------------------------------------------------------------------------
__launch_bounds__(256)
__global__ void filter_mlp_kernel(const float* __restrict__ z,
                                  const float* __restrict__ fin_W,
                                  const float* __restrict__ fin_b,
                                  const float* __restrict__ freq,
                                  const float* __restrict__ mid_W,
                                  const float* __restrict__ mid_b,
                                  float* __restrict__ k3out)
{
    __shared__ __align__(16) float W1[PE_DIM*MLP_W];    // 16.6 KB
    __shared__ __align__(16) float Wm[2*MLP_W*MLP_W];   // 32 KB
    __shared__ __align__(16) float zs[16*PE_DIM];       // 4.2 KB
    __shared__ __align__(16) float kb[2][16*MLP_W];     // 8 KB
    int tid = threadIdx.x;
    int t0 = blockIdx.x * 16;
    for (int i = tid; i < PE_DIM*MLP_W; i += 256) W1[i] = fin_W[i];
    for (int i = tid; i < 2*MLP_W*MLP_W; i += 256) Wm[i] = mid_W[i];
    for (int i = tid; i < 16*PE_DIM; i += 256) zs[i] = z[(size_t)t0*PE_DIM + i];
    __syncthreads();

    int j = tid & 63, tl = tid >> 6;   // j: output unit, tl: 0..3 (t = tl+4*tt)
    float fj = freq[j];
    float a[4];

    // layer 1: z(65) -> 64, sin
    {
        float fb = fin_b[j];
        #pragma unroll
        for (int tt = 0; tt < 4; ++tt) a[tt] = fb;
        for (int i = 0; i < PE_DIM; ++i) {
            float w = W1[i*MLP_W + j];                   // coalesced
            #pragma unroll
            for (int tt = 0; tt < 4; ++tt)
                a[tt] += zs[(tl + 4*tt)*PE_DIM + i] * w; // broadcast
        }
        #pragma unroll
        for (int tt = 0; tt < 4; ++tt)
            kb[0][(tl + 4*tt)*MLP_W + j] = sinf(fj*a[tt]);
    }
    __syncthreads();
    // layer 2
    {
        float mb = mid_b[j];
        #pragma unroll
        for (int tt = 0; tt < 4; ++tt) a[tt] = mb;
        for (int i = 0; i < MLP_W; ++i) {
            float w = Wm[i*MLP_W + j];
            #pragma unroll
            for (int tt = 0; tt < 4; ++tt)
                a[tt] += kb[0][(tl + 4*tt)*MLP_W + i] * w;
        }
        #pragma unroll
        for (int tt = 0; tt < 4; ++tt)
            kb[1][(tl + 4*tt)*MLP_W + j] = sinf(fj*a[tt]);
    }
    __syncthreads();
    // layer 3 -> global k3
    {
        float mb = mid_b[MLP_W + j];
        #pragma unroll
        for (int tt = 0; tt < 4; ++tt) a[tt] = mb;
        for (int i = 0; i < MLP_W; ++i) {
            float w = Wm[MLP_W*MLP_W + i*MLP_W + j];
            #pragma unroll
            for (int tt = 0; tt < 4; ++tt)
                a[tt] += kb[1][(tl + 4*tt)*MLP_W + i] * w;
        }
        #pragma unroll
        for (int tt = 0; tt < 4; ++tt)
            k3out[(size_t)(t0 + tl + 4*tt)*MLP_W + j] = sinf(fj*a[tt]); // coalesced
    }
}

// ---------------------------------------------------------------------------
// K1b: hTt[t,d] = (k3[t,:] @ fout_W[:,d]) * decay(t,d).
// ---------------------------------------------------------------------------
__launch_bounds__(256)
__global__ void filter_out_kernel(const float* __restrict__ k3,
                                  const float* __restrict__ fout_W,
                                  float* __restrict__ hTt)
{
    __shared__ __align__(16) float ks[64*64];    // [t][i] 16 KB
    __shared__ __align__(16) float fs[64*132];   // [i][d] padded, 33.8 KB
    int tid = threadIdx.x;
    int d0 = blockIdx.x * 128;
    int t0 = blockIdx.y * 64;

    for (int q = tid; q < 1024; q += 256)        // 4096 floats of k3 tile
        *(f4*)&ks[q*4] = *(const f4*)&k3[(size_t)t0*MLP_W + q*4];
    for (int q = tid; q < 2048; q += 256) {      // 64 rows x 32 f4 of fout tile
        int i = q >> 5, c = q & 31;
        *(f4*)&fs[i*132 + c*4] = *(const f4*)&fout_W[(size_t)i*D_MODEL + d0 + c*4];
    }
    __syncthreads();

    int c = tid & 31;            // d sub-block: d = d0 + 4c + dd
    int t_base = (tid >> 5)*8;   // 8 t per thread
    f4 acc[8];
    #pragma unroll
    for (int tt = 0; tt < 8; ++tt) acc[tt] = (f4){0.f,0.f,0.f,0.f};

    for (int i = 0; i < MLP_W; ++i) {
        f4 fv = *(const f4*)&fs[i*132 + c*4];
        #pragma unroll
        for (int tt = 0; tt < 8; ++tt) {
            float kv = ks[(t_base + tt)*MLP_W + i];   // 2-way broadcast per wave
            acc[tt][0] += kv * fv[0];
            acc[tt][1] += kv * fv[1];
            acc[tt][2] += kv * fv[2];
            acc[tt][3] += kv * fv[3];
        }
    }

    const float MIND = -3.0701134573253944f;   // ln(0.01)/1.5
    const float MAXD = -15.350567286626972f;   // ln(0.01)/0.3
    #pragma unroll
    for (int tt = 0; tt < 8; ++tt) {
        int t = t0 + t_base + tt;
        float ttf = (float)t * (1.0f/(float)(MAX_LEN-1));
        f4 o;
        #pragma unroll
        for (int dd = 0; dd < 4; ++dd) {
            int d = d0 + 4*c + dd;
            float delta = MIND + (MAXD-MIND)*((float)d*(1.0f/(float)(D_MODEL-1)));
            o[dd] = acc[tt][dd] * expf(-ttf*fabsf(delta));
        }
        *(f4*)&hTt[(size_t)t*D_MODEL + d0 + 4*c] = o;   // coalesced f4
    }
}

// ---------------------------------------------------------------------------
// cast fp32 -> bf16 (elementwise, 8/thread)
// ---------------------------------------------------------------------------
__global__ void cast_bf16_kernel(const float* __restrict__ src,
                                 u16* __restrict__ dst, int n)
{
    int i = (blockIdx.x*256 + threadIdx.x)*8;
    if (i + 7 >= n) {
        for (int j = i; j < n; ++j) dst[j] = f2bf(src[j]);
        return;
    }
    float4 a = *(const float4*)(src + i);
    float4 b = *(const float4*)(src + i + 4);
    uint4 o;
    o.x = pk2(a.x, a.y);
    o.y = pk2(a.z, a.w);
    o.z = pk2(b.x, b.y);
    o.w = pk2(b.z, b.w);
    *(uint4*)(dst + i) = o;
}

// ---------------------------------------------------------------------------
// transpose + cast: src (R x C fp32) -> dst (C x R bf16)
// ---------------------------------------------------------------------------
__global__ void transpose_cast_kernel(const float* __restrict__ src,
                                      u16* __restrict__ dst, int R, int C)
{
    __shared__ u16 tile[64][65];
    int c0 = blockIdx.x*64, r0 = blockIdx.y*64;
    int tid = threadIdx.x;
    #pragma unroll
    for (int p = 0; p < 16; ++p) {
        int idx = tid + 256*p;
        int rr = idx >> 6, cc = idx & 63;
        tile[rr][cc] = f2bf(src[(size_t)(r0+rr)*C + c0 + cc]);
    }
    __syncthreads();
    #pragma unroll
    for (int p = 0; p < 16; ++p) {
        int idx = tid + 256*p;
        int cr = idx >> 6, rc = idx & 63;
        dst[(size_t)(c0+cr)*R + r0 + rc] = tile[rc][cr];
    }
}

// ---------------------------------------------------------------------------
// K2/K6: C[M,N] = A[M,K]bf16 @ Bt[N,K]bf16 + bias.
// v6 = v5 with the waits moved to just-in-time per HALF-tile (v5 post-mortem:
// single vmcnt(4) at q3 gave the newest chunk only 2 phases of slack -> every
// K-tile stalled ~mem-latency at q3 with all waves barrier-blocked; MfmaUtil
// stuck at 24% with 0 bank conflicts).
//   W1(kt) = vmcnt(8) in (kt-1).q3 wait slot: covers kt.kk0 {A,B}, issued at
//            (kt-2).q2/q3 -> 5 phases slack. Published by q3's open barrier,
//            consumed at kt.q0 after q3's close barrier.
//   W2(kt) = vmcnt(8) in kt.q1 wait slot: covers kt.kk1 {A,B}, issued at
//            (kt-1).q0/q1 -> 5 phases slack. Published by q1's open barrier,
//            consumed at kt.q2.
// Ledger (8 GLDS instr/tile, 12 outstanding steady): both waits leave exactly
// the 8 newest (= two not-yet-needed half-tiles) in flight; robust to any
// VMEM hoisted above the loop. Tail: W1(NT-1)=vmcnt(4) at (NT-2).q3,
// W2(NT-1)=vmcnt(0), no wait at (NT-1).q3.
// Staging, T2 swizzle, accumulation order unchanged -> bit-identical output.
// ---------------------------------------------------------------------------
__launch_bounds__(512, 2)
__global__ void gemm_mfma256_kernel(const u16* __restrict__ A,   // M x K
                                    const u16* __restrict__ Bt,  // N x K
                                    const float* __restrict__ bias,
                                    float* __restrict__ C,
                                    int M, int N, int K)
{
    __shared__ __align__(16) u16 lds[65536];   // 128 KiB

    // XCD swizzle (bijective: nwg % 8 == 0 at both call sites)
    int nwg = gridDim.x * gridDim.y;
    int bid = blockIdx.y * gridDim.x + blockIdx.x;
    int cpx = nwg >> 3;
    int swz = (bid & 7) * cpx + (bid >> 3);
    int bx = swz % gridDim.x, by = swz / gridDim.x;
    int m0 = by * 256, n0 = bx * 256;

    int tid = threadIdx.x;
    int lane = tid & 63, w = tid >> 6;         // 8 waves
    int lrow = lane & 15, lch = lane >> 4;
    int wm = (w >> 2) * 128;                   // M-half of wave
    int wn = (w & 3) * 64;                     // N-quarter of wave
    int lchx8 = (lch ^ ((lrow >> 1) & 3)) * 8; // swizzled 16B-slot selector

    // staging: wave w owns rows [32w, 32w+32) of each 256-row sub-tile;
    // 2 calls per sub-tile (16 rows each). Source col pre-swizzled so the
    // linear GLDS landing realizes the XOR layout.
    int srow = 32*w + (lane >> 2);             // +16 for second call
    int scol = ((lane & 3) ^ ((lane >> 3) & 3))*8;
    const u16* baseA = A  + (size_t)(m0 + srow)*K + scol;
    const u16* baseB = Bt + (size_t)(n0 + srow)*K + scol;

    // LDS layout (u16 units): buf*32768 + op*16384 + kk*8192 + row*32 + swz(col)
    auto stageA = [&](int kt_, int kk_) {
        u16* dst = lds + (size_t)(((kt_ & 1) << 15) + (kk_ << 13) + (w << 10));
        const u16* src = baseA + (size_t)kt_*64 + (size_t)kk_*32;
        GLDS16(src, dst);
        GLDS16(src + 16*(size_t)K, dst + 512);
    };
    auto stageB = [&](int kt_, int kk_) {
        u16* dst = lds + (size_t)(16384 + ((kt_ & 1) << 15) + (kk_ << 13) + (w << 10));
        const u16* src = baseB + (size_t)kt_*64 + (size_t)kk_*32;
        GLDS16(src, dst);
        GLDS16(src + 16*(size_t)K, dst + 512);
    };

    f32x4 acc[8][4];
    #pragma unroll
    for (int i = 0; i < 8; ++i)
        #pragma unroll
        for (int j = 0; j < 4; ++j)
            acc[i][j] = (f32x4){0.f,0.f,0.f,0.f};

    int NT = K >> 6;   // K-tiles of 64 (12 at both call sites)

    // prologue: kt0 full + kt1.kk0  (12 GLDS instrs/wave outstanding)
    stageA(0, 0); stageB(0, 0);
    stageA(0, 1); stageB(0, 1);
    stageA(1, 0); stageB(1, 0);
    asm volatile("s_waitcnt vmcnt(8)" ::: "memory");   // W1(0): kt0.kk0 landed
    __builtin_amdgcn_s_barrier();                      // publish
    asm volatile("" ::: "memory");

    bf16x8 bfr[4];

#define PHASE(mh, kk, STAGE_STMT, LOADB, WAIT_STMT)                             \
    {                                                                           \
        bf16x8 af[4];                                                           \
        _Pragma("unroll")                                                       \
        for (int i = 0; i < 4; ++i)                                             \
            af[i] = *(const bf16x8*)&lds[bsel + ((kk) << 13)                    \
                     + (wm + (mh)*64 + i*16 + lrow)*32 + lchx8];                \
        if (LOADB) {                                                            \
            _Pragma("unroll")                                                   \
            for (int j = 0; j < 4; ++j)                                         \
                bfr[j] = *(const bf16x8*)&lds[bsel + 16384 + ((kk) << 13)       \
                          + (wn + j*16 + lrow)*32 + lchx8];                     \
        }                                                                       \
        STAGE_STMT;                                                             \
        WAIT_STMT;                                                              \
        asm volatile("" ::: "memory");                                          \
        __builtin_amdgcn_s_barrier();                                           \
        __builtin_amdgcn_s_setprio(1);                                          \
        _Pragma("unroll")                                                       \
        for (int i = 0; i < 4; ++i)                                             \
            _Pragma("unroll")                                                   \
            for (int j = 0; j < 4; ++j)                                         \
                acc[(mh)*4 + i][j] = __builtin_amdgcn_mfma_f32_16x16x32_bf16(   \
                    af[i], bfr[j], acc[(mh)*4 + i][j], 0, 0, 0);                \
        __builtin_amdgcn_s_setprio(0);                                          \
        __builtin_amdgcn_s_barrier();                                           \
        asm volatile("" ::: "memory");                                          \
    }

    #pragma unroll 1
    for (int kt = 0; kt < NT; ++kt) {
        const int bsel = (kt & 1) << 15;
        // q0: stage kt+1.kk1 A
        PHASE(0, 0, if (kt + 1 < NT) stageA(kt + 1, 1), 1, )
        // q1: stage kt+1.kk1 B ; W2(kt) covers kt.kk1 before q2 reads it
        if (kt < NT - 1) {
            PHASE(1, 0, stageB(kt + 1, 1), 0,
                  asm volatile("s_waitcnt vmcnt(8)" ::: "memory"))
        } else {
            PHASE(1, 0, , 0,
                  asm volatile("s_waitcnt vmcnt(0)" ::: "memory"))
        }
        // q2: stage kt+2.kk0 A
        PHASE(0, 1, if (kt + 2 < NT) stageA(kt + 2, 0), 1, )
        // q3: stage kt+2.kk0 B ; W1(kt+1) covers kt+1.kk0 before next q0
        if (kt < NT - 2) {
            PHASE(1, 1, stageB(kt + 2, 0), 0,
                  asm volatile("s_waitcnt vmcnt(8)" ::: "memory"))
        } else if (kt == NT - 2) {
            PHASE(1, 1, , 0,
                  asm volatile("s_waitcnt vmcnt(4)" ::: "memory"))
        } else {
            PHASE(1, 1, , 0, )
        }
    }
#undef PHASE

    // epilogue: bias + fp32 stores
    #pragma unroll
    for (int nt = 0; nt < 4; ++nt) {
        int n = n0 + wn + nt*16 + lrow;
        float bv = bias[n];
        #pragma unroll
        for (int mt = 0; mt < 8; ++mt) {
            int m = m0 + wm + mt*16 + lch*4;
            #pragma unroll
            for (int r = 0; r < 4; ++r)
                C[(size_t)(m + r)*N + n] = acc[mt][nt][r] + bv;
        }
    }
}

// ---------------------------------------------------------------------------
// K3: short conv (width 3, causal) + split; seq=x0*v -> bf16 (B,768,L),
// gate=x1 -> fp32 (B*L,768)
// ---------------------------------------------------------------------------
__global__ void convprep_kernel(const float* __restrict__ up,
                                const float* __restrict__ conv_W,
                                const float* __restrict__ conv_b,
                                u16* __restrict__ seqbf,
                                float* __restrict__ gate)
{
    __shared__ float sb[64][65];
    int d0 = blockIdx.x * 64;
    int t0 = blockIdx.y * 64;
    int b  = blockIdx.z;
    int tid = threadIdx.x;
    #pragma unroll
    for (int i = 0; i < 16; ++i) {
        int idx = tid + 256*i;
        int trow = idx >> 6, dcol = idx & 63;
        int t = t0 + trow;
        int d = d0 + dcol;
        size_t r = ((size_t)b*MAX_LEN + t)*D3;
        float uc[3];
        #pragma unroll
        for (int g = 0; g < 3; ++g) {
            int c = d + g*D_MODEL;
            float u0 = up[r + c];
            float u1 = (t >= 1) ? up[r - D3 + c]   : 0.f;
            float u2 = (t >= 2) ? up[r - 2*D3 + c] : 0.f;
            uc[g] = conv_W[c]*u2 + conv_W[D3 + c]*u1 + conv_W[2*D3 + c]*u0 + conv_b[c];
        }
        sb[trow][dcol] = uc[0]*uc[2];
        gate[((size_t)b*MAX_LEN + t)*D_MODEL + d] = uc[1];
    }
    __syncthreads();
    #pragma unroll
    for (int i = 0; i < 16; ++i) {
        int idx = tid + 256*i;
        int drow = idx >> 6, tcol = idx & 63;
        seqbf[((size_t)b*D_MODEL + d0 + drow)*MAX_LEN + t0 + tcol] = f2bf(sb[tcol][drow]);
    }
}

// ---------------------------------------------------------------------------
// K4: long causal depthwise conv via block-Toeplitz MFMA (delta-factorized).
// ---------------------------------------------------------------------------
__launch_bounds__(256)
__global__ void longconv_mfma_kernel(const u16* __restrict__ seqbf, // (B,768,L) bf16
                                     const u16* __restrict__ hbf,   // (768,L) bf16
                                     const float* __restrict__ filt_bias,
                                     float* __restrict__ yT)        // (B,768,L) fp32
{
    __shared__ __align__(16) u16 sq[4*4896];   // per-batch swizzled seq, 256-elem zero pad below
    __shared__ __align__(16) u16 hp[4112];     // bf16 h, 16-elem zero pad below
    __shared__ __align__(16) u16 A_s[16*648];  // 16 slabs = rounds 0..15 at segment s

    int d   = blockIdx.x;
    int tid = threadIdx.x;
    int lane = tid & 63, w = tid >> 6;         // w = batch
    int lrow = lane & 15, lch = lane >> 4;

    // stage seq for all 4 batches (9/8 swizzle expansion) + h (shared per d)
    for (int q = tid; q < 4*544; q += 256) {
        int b = q / 544, qq = q - b*544;       // 32 pad quads + 512 data per batch
        int p = b*4896 + ((qq + (qq >> 3)) << 3);
        uint4 o = make_uint4(0u,0u,0u,0u);
        if (qq >= 32) o = *(const uint4*)&seqbf[((size_t)b*D_MODEL + d)*MAX_LEN + (size_t)(qq-32)*8];
        *(uint4*)&sq[p] = o;
    }
    for (int q = tid; q < 514; q += 256) {     // 2 pad quads + 512 data
        uint4 o = make_uint4(0u,0u,0u,0u);
        if (q >= 2) o = *(const uint4*)&hbf[(size_t)d*MAX_LEN + (size_t)(q-2)*8];
        *(uint4*)&hp[q*8] = o;
    }

    f32x4 acc[16];
    #pragma unroll
    for (int g = 0; g < 16; ++g) acc[g] = (f32x4){0.f,0.f,0.f,0.f};

    // slab build: thread -> (round slab_b, row i_b); 16 threads per slab
    int slab_b = tid >> 4;                     // 0..15 = round r
    int i_b    = tid & 15;
    int rot    = (slab_b & 3)*4;               // bank-stagger for the 4 groups/wave
    u32* bld = (u32*)&A_s[slab_b*648 + i_b*40];

    const char* sqb = (const char*)(sq + w*4896);   // per-wave (batch) base
    int Q0 = 30 + 2*lrow + lch;                     // = (240+16lrow+8lch)/8

#define MM(af_, bf_, gi) acc[gi] = __builtin_amdgcn_mfma_f32_16x16x32_bf16(af_, bf_, acc[gi], 0, 0, 0)

    #pragma unroll 1
    for (int s = 0; s < 8; ++s) {
        __syncthreads();   // prior segment's A_s reads done (and staging on s=0)
        {   // build 16 slabs: A(r)[i][k] = hp[32 + 256r + 32s + i - k], k=0..31
            int hbase = 32 + 256*slab_b + 32*s + i_b;
            #pragma unroll
            for (int j = 0; j < 16; ++j) {
                int kk = (j + rot) & 15;
                u16 v0 = hp[hbase - 2*kk];
                u16 v1 = hp[hbase - 2*kk - 1];
                bld[kk] = (u32)v0 | ((u32)v1 << 16);
            }
        }
        __syncthreads();
        bf16x8 aR[16];
        #pragma unroll
        for (int r = 0; r < 16; ++r)
            aR[r] = *(const bf16x8*)&A_s[r*648 + lrow*40 + lch*8];
        int Qs = Q0 - 4*s;                              // >= 2, no negatives
        const char* bp = sqb + (Qs*16 + (Qs >> 3)*16);  // swizzled base
        #pragma unroll
        for (int dlt = 0; dlt < 16; ++dlt) {
            bf16x8 F = *(const bf16x8*)(bp + 576*dlt);  // exact through swizzle
            #pragma unroll
            for (int r = 0; r < 16 - dlt; ++r)
                MM(aR[r], F, r + dlt);
        }
    }
#undef MM

    // epilogue: y = acc + filt_bias[d]*seq ; write fp32 to yT
    float fb = filt_bias[d];
    const u16* sqbu = sq + w*4896;
    float* dsty = yT + ((size_t)w*D_MODEL + d)*MAX_LEN;
    #pragma unroll
    for (int g = 0; g < 16; ++g) {
        int t0 = 256*g + 16*lrow + 4*lch;
        int elem = 256 + t0;                 // multiple of 4; 4 elems in one quad
        int Q = elem >> 3;
        const u16* pv = &sqbu[(((Q + (Q >> 3)) << 3)) | (elem & 7)];
        ushort4 sv = *(const ushort4*)pv;    // 8B aligned
        f4 o;
        o[0] = acc[g][0] + fb*bf2f(sv.x);
        o[1] = acc[g][1] + fb*bf2f(sv.y);
        o[2] = acc[g][2] + fb*bf2f(sv.z);
        o[3] = acc[g][3] + fb*bf2f(sv.w);
        *(f4*)&dsty[t0] = o;
    }
}

// ---------------------------------------------------------------------------
// K5: Afin(bf16)[b*L+t, d] = yT[b,d,t] * gate[b*L+t, d]
// ---------------------------------------------------------------------------
__global__ void gatemul_kernel(const float* __restrict__ yT,
                               const float* __restrict__ gate,
                               u16* __restrict__ Afin)
{
    __shared__ float tb[64][65];
    int d0 = blockIdx.x * 64;
    int t0 = blockIdx.y * 64;
    int b  = blockIdx.z;
    int tid = threadIdx.x;
    #pragma unroll
    for (int i = 0; i < 16; ++i) {
        int idx = tid + 256*i;
        int drow = idx >> 6, tcol = idx & 63;
        tb[drow][tcol] = yT[((size_t)b*D_MODEL + d0 + drow)*MAX_LEN + t0 + tcol];
    }
    __syncthreads();
    #pragma unroll
    for (int i = 0; i < 16; ++i) {
        int idx = tid + 256*i;
        int trow = idx >> 6, dcol = idx & 63;
        size_t r = ((size_t)b*MAX_LEN + t0 + trow)*D_MODEL + d0 + dcol;
        Afin[r] = f2bf(tb[dcol][trow] * gate[r]);
    }
}

// ---------------------------------------------------------------------------
extern "C" void kernel_launch(void* const* d_in, const int* in_sizes, int n_in,
                              void* d_out, int out_size, void* d_ws, size_t ws_size,
                              hipStream_t stream)
{
    (void)in_sizes; (void)n_in; (void)out_size; (void)ws_size;
    const float* u      = (const float*)d_in[0];
    const float* z      = (const float*)d_in[1];
    const float* fin_W  = (const float*)d_in[2];
    const float* fin_b  = (const float*)d_in[3];
    const float* freq   = (const float*)d_in[4];
    const float* mid_W  = (const float*)d_in[5];
    const float* mid_b  = (const float*)d_in[6];
    const float* fout_W = (const float*)d_in[7];
    const float* proj_W = (const float*)d_in[8];
    const float* proj_b = (const float*)d_in[9];
    const float* conv_W = (const float*)d_in[10];
    const float* conv_b = (const float*)d_in[11];
    const float* fbias  = (const float*)d_in[12];
    const float* out_W  = (const float*)d_in[13];
    const float* out_b  = (const float*)d_in[14];
    float* out = (float*)d_out;

    // ws layout (floats), total 65,667,072 f = 262.7 MB:
    float* ws    = (float*)d_ws;
    u16*   hbf   = (u16*)ws;                          // 3,145,728 u16 = 1,572,864 f
    float* up    = ws + 1572864;                      // 37,748,736 f
    float* gate  = up + 37748736;                     // 12,582,912 f
    u16*   seqbf = (u16*)(gate + 12582912);           // 12,582,912 u16 = 6,291,456 f
    u16*   Abf   = (u16*)(gate + 12582912 + 6291456); // 12,582,912 u16 = 6,291,456 f
    u16*   BpT1  = (u16*)(gate + 12582912 + 2*6291456);          // 884,736 f
    u16*   BpT2  = (u16*)(gate + 12582912 + 2*6291456 + 884736); // 294,912 f
    // aliases in regions dead at time of use:
    float* hTt   = up;                    // t-major h; dead before GEMM1 writes up
    float* yT    = up;                    // longconv out; up fp32 dead after convprep
    u16*   Afinbf= (u16*)(up + 16777216); // gatemul out; disjoint from yT (12.58M f)
    float* k3buf = gate;                  // 1 MB; gate region dead until convprep

    filter_mlp_kernel<<<MAX_LEN/16, 256, 0, stream>>>(z, fin_W, fin_b, freq,
                                                      mid_W, mid_b, k3buf);
    filter_out_kernel<<<dim3(D_MODEL/128, MAX_LEN/64), 256, 0, stream>>>(
        k3buf, fout_W, hTt);
    transpose_cast_kernel<<<dim3(D_MODEL/64, MAX_LEN/64), 256, 0, stream>>>(
        hTt, hbf, MAX_LEN, D_MODEL);
    cast_bf16_kernel<<<(ROWS*D_MODEL)/(256*8), 256, 0, stream>>>(u, Abf, ROWS*D_MODEL);
    transpose_cast_kernel<<<dim3(D3/64, D_MODEL/64), 256, 0, stream>>>(
        proj_W, BpT1, D_MODEL, D3);
    gemm_mfma256_kernel<<<dim3(D3/256, ROWS/256), 512, 0, stream>>>(
        Abf, BpT1, proj_b, up, ROWS, D3, D_MODEL);
    convprep_kernel<<<dim3(D_MODEL/64, MAX_LEN/64, NBATCH), 256, 0, stream>>>(
        up, conv_W, conv_b, seqbf, gate);
    transpose_cast_kernel<<<dim3(D_MODEL/64, D_MODEL/64), 256, 0, stream>>>(
        out_W, BpT2, D_MODEL, D_MODEL);
    longconv_mfma_kernel<<<D_MODEL, 256, 0, stream>>>(seqbf, hbf, fbias, yT);
    gatemul_kernel<<<dim3(D_MODEL/64, MAX_LEN/64, NBATCH), 256, 0, stream>>>(
        yT, gate, Afinbf);
    gemm_mfma256_kernel<<<dim3(D_MODEL/256, ROWS/256), 512, 0, stream>>>(
        Afinbf, BpT2, out_b, out, ROWS, D_MODEL, D_MODEL);
}

// Round 8
// 389.520 us; speedup vs baseline: 1.0209x; 1.0209x over previous
//
#include <hip/hip_runtime.h>
#include <math.h>

#define MAX_LEN 4096
#define D_MODEL 768
#define PE_DIM 65
#define MLP_W 64
#define NBATCH 4
#define D3 2304               // (ORDER+1)*D_MODEL
#define ROWS (NBATCH*MAX_LEN) // 16384

typedef unsigned short u16;
typedef unsigned int u32;
typedef float f4 __attribute__((ext_vector_type(4)));
typedef __bf16 bf16x8 __attribute__((ext_vector_type(8)));
typedef float f32x4 __attribute__((ext_vector_type(4)));

__device__ inline u16 f2bf(float x) {
    u32 u = __float_as_uint(x);
    u += 0x7fffu + ((u >> 16) & 1u);   // round-to-nearest-even
    return (u16)(u >> 16);
}
__device__ inline float bf2f(u16 v) { return __uint_as_float((u32)v << 16); }
__device__ inline u32 pk2(float a, float b) {
    return (u32)f2bf(a) | ((u32)f2bf(b) << 16);
}

// direct global->LDS async copy, 16B per lane; lds base must be wave-uniform.
// One call moves 64 lanes x 16B = 1KB, landing at ldsbase + lane*16B.
#define GLDS16(gp, lp) __builtin_amdgcn_global_load_lds( \
    (const __attribute__((address_space(1))) u32*)(gp), \
    (__attribute__((address_space(3))) u32*)(lp), 16, 0, 0)

// ---------------------------------------------------------------------------
// K1a: 3-layer sin-MLP -> k3 (MAX_LEN x 64 fp32).
// ---------------------------------------------------------------------------
__launch_bounds__(256)
__global__ void filter_mlp_kernel(const float* __restrict__ z,
                                  const float* __restrict__ fin_W,
                                  const float* __restrict__ fin_b,
                                  const float* __restrict__ freq,
                                  const float* __restrict__ mid_W,
                                  const float* __restrict__ mid_b,
                                  float* __restrict__ k3out)
{
    __shared__ __align__(16) float W1[PE_DIM*MLP_W];    // 16.6 KB
    __shared__ __align__(16) float Wm[2*MLP_W*MLP_W];   // 32 KB
    __shared__ __align__(16) float zs[16*PE_DIM];       // 4.2 KB
    __shared__ __align__(16) float kb[2][16*MLP_W];     // 8 KB
    int tid = threadIdx.x;
    int t0 = blockIdx.x * 16;
    for (int i = tid; i < PE_DIM*MLP_W; i += 256) W1[i] = fin_W[i];
    for (int i = tid; i < 2*MLP_W*MLP_W; i += 256) Wm[i] = mid_W[i];
    for (int i = tid; i < 16*PE_DIM; i += 256) zs[i] = z[(size_t)t0*PE_DIM + i];
    __syncthreads();

    int j = tid & 63, tl = tid >> 6;   // j: output unit, tl: 0..3 (t = tl+4*tt)
    float fj = freq[j];
    float a[4];

    // layer 1: z(65) -> 64, sin
    {
        float fb = fin_b[j];
        #pragma unroll
        for (int tt = 0; tt < 4; ++tt) a[tt] = fb;
        for (int i = 0; i < PE_DIM; ++i) {
            float w = W1[i*MLP_W + j];                   // coalesced
            #pragma unroll
            for (int tt = 0; tt < 4; ++tt)
                a[tt] += zs[(tl + 4*tt)*PE_DIM + i] * w; // broadcast
        }
        #pragma unroll
        for (int tt = 0; tt < 4; ++tt)
            kb[0][(tl + 4*tt)*MLP_W + j] = sinf(fj*a[tt]);
    }
    __syncthreads();
    // layer 2
    {
        float mb = mid_b[j];
        #pragma unroll
        for (int tt = 0; tt < 4; ++tt) a[tt] = mb;
        for (int i = 0; i < MLP_W; ++i) {
            float w = Wm[i*MLP_W + j];
            #pragma unroll
            for (int tt = 0; tt < 4; ++tt)
                a[tt] += kb[0][(tl + 4*tt)*MLP_W + i] * w;
        }
        #pragma unroll
        for (int tt = 0; tt < 4; ++tt)
            kb[1][(tl + 4*tt)*MLP_W + j] = sinf(fj*a[tt]);
    }
    __syncthreads();
    // layer 3 -> global k3
    {
        float mb = mid_b[MLP_W + j];
        #pragma unroll
        for (int tt = 0; tt < 4; ++tt) a[tt] = mb;
        for (int i = 0; i < MLP_W; ++i) {
            float w = Wm[MLP_W*MLP_W + i*MLP_W + j];
            #pragma unroll
            for (int tt = 0; tt < 4; ++tt)
                a[tt] += kb[1][(tl + 4*tt)*MLP_W + i] * w;
        }
        #pragma unroll
        for (int tt = 0; tt < 4; ++tt)
            k3out[(size_t)(t0 + tl + 4*tt)*MLP_W + j] = sinf(fj*a[tt]); // coalesced
    }
}

// ---------------------------------------------------------------------------
// K1b (fused transpose): hbf[d][t] = bf16((k3[t,:] @ fout_W[:,d]) * decay).
// v2: was hTt fp32 (t-major) + separate transpose_cast kernel. Now the fp32
// result is staged in LDS (fs reused as ht[64][132] after a barrier) and
// stored transposed as bf16 directly. Same f2bf of the same fp32 -> values
// bit-identical; saves 12.6MB w + 12.6MB r + 6.3MB w and one launch.
// ---------------------------------------------------------------------------
__launch_bounds__(256)
__global__ void filter_out_kernel(const float* __restrict__ k3,
                                  const float* __restrict__ fout_W,
                                  u16* __restrict__ hbf)   // (768,4096) d-major
{
    __shared__ __align__(16) float ks[64*64];    // [t][i] 16 KB
    __shared__ __align__(16) float fs[64*132];   // [i][d] padded; reused as ht
    int tid = threadIdx.x;
    int d0 = blockIdx.x * 128;
    int t0 = blockIdx.y * 64;

    for (int q = tid; q < 1024; q += 256)        // 4096 floats of k3 tile
        *(f4*)&ks[q*4] = *(const f4*)&k3[(size_t)t0*MLP_W + q*4];
    for (int q = tid; q < 2048; q += 256) {      // 64 rows x 32 f4 of fout tile
        int i = q >> 5, c = q & 31;
        *(f4*)&fs[i*132 + c*4] = *(const f4*)&fout_W[(size_t)i*D_MODEL + d0 + c*4];
    }
    __syncthreads();

    int c = tid & 31;            // d sub-block: d = d0 + 4c + dd
    int t_base = (tid >> 5)*8;   // 8 t per thread
    f4 acc[8];
    #pragma unroll
    for (int tt = 0; tt < 8; ++tt) acc[tt] = (f4){0.f,0.f,0.f,0.f};

    for (int i = 0; i < MLP_W; ++i) {
        f4 fv = *(const f4*)&fs[i*132 + c*4];
        #pragma unroll
        for (int tt = 0; tt < 8; ++tt) {
            float kv = ks[(t_base + tt)*MLP_W + i];   // 2-way broadcast per wave
            acc[tt][0] += kv * fv[0];
            acc[tt][1] += kv * fv[1];
            acc[tt][2] += kv * fv[2];
            acc[tt][3] += kv * fv[3];
        }
    }

    const float MIND = -3.0701134573253944f;   // ln(0.01)/1.5
    const float MAXD = -15.350567286626972f;   // ln(0.01)/0.3
    __syncthreads();   // all fs reads done before reuse as ht
    #pragma unroll
    for (int tt = 0; tt < 8; ++tt) {
        int t = t0 + t_base + tt;
        float ttf = (float)t * (1.0f/(float)(MAX_LEN-1));
        f4 o;
        #pragma unroll
        for (int dd = 0; dd < 4; ++dd) {
            int d = d0 + 4*c + dd;
            float delta = MIND + (MAXD-MIND)*((float)d*(1.0f/(float)(D_MODEL-1)));
            o[dd] = acc[tt][dd] * expf(-ttf*fabsf(delta));
        }
        *(f4*)&fs[(t_base + tt)*132 + 4*c] = o;   // ht[t_local][d_local]
    }
    __syncthreads();
    // transposed bf16 store: hbf[d0+dr][t0 + 4*c4 .. +3]
    #pragma unroll
    for (int p = 0; p < 8; ++p) {
        int chunk = tid + 256*p;       // 0..2047 over 128 dr x 16 c4
        int dr = chunk >> 4;
        int c4 = chunk & 15;
        ushort4 o;
        o.x = f2bf(fs[(c4*4 + 0)*132 + dr]);
        o.y = f2bf(fs[(c4*4 + 1)*132 + dr]);
        o.z = f2bf(fs[(c4*4 + 2)*132 + dr]);
        o.w = f2bf(fs[(c4*4 + 3)*132 + dr]);
        *(ushort4*)&hbf[(size_t)(d0 + dr)*MAX_LEN + t0 + c4*4] = o;
    }
}

// ---------------------------------------------------------------------------
// cast fp32 -> bf16 (elementwise, 8/thread)
// ---------------------------------------------------------------------------
__global__ void cast_bf16_kernel(const float* __restrict__ src,
                                 u16* __restrict__ dst, int n)
{
    int i = (blockIdx.x*256 + threadIdx.x)*8;
    if (i + 7 >= n) {
        for (int j = i; j < n; ++j) dst[j] = f2bf(src[j]);
        return;
    }
    float4 a = *(const float4*)(src + i);
    float4 b = *(const float4*)(src + i + 4);
    uint4 o;
    o.x = pk2(a.x, a.y);
    o.y = pk2(a.z, a.w);
    o.z = pk2(b.x, b.y);
    o.w = pk2(b.z, b.w);
    *(uint4*)(dst + i) = o;
}

// ---------------------------------------------------------------------------
// transpose + cast: src (R x C fp32) -> dst (C x R bf16)
// ---------------------------------------------------------------------------
__global__ void transpose_cast_kernel(const float* __restrict__ src,
                                      u16* __restrict__ dst, int R, int C)
{
    __shared__ u16 tile[64][65];
    int c0 = blockIdx.x*64, r0 = blockIdx.y*64;
    int tid = threadIdx.x;
    #pragma unroll
    for (int p = 0; p < 16; ++p) {
        int idx = tid + 256*p;
        int rr = idx >> 6, cc = idx & 63;
        tile[rr][cc] = f2bf(src[(size_t)(r0+rr)*C + c0 + cc]);
    }
    __syncthreads();
    #pragma unroll
    for (int p = 0; p < 16; ++p) {
        int idx = tid + 256*p;
        int cr = idx >> 6, rc = idx & 63;
        dst[(size_t)(c0+cr)*R + r0 + rc] = tile[rc][cr];
    }
}

// ---------------------------------------------------------------------------
// K2/K6: C[M,N] = A[M,K]bf16 @ Bt[N,K]bf16 + bias.
// v7 = exact revert to the v5 schedule (best measured: 98us, MfmaUtil 24,
// bank-conflicts 0). v6's split JIT waits regressed (108us) -> schedule knob
// exhausted at this shape (K=768: NT=12 short pipeline; grid 576 = 2.25
// rounds caps utilization at 75%). 256x256, 8 waves 2Mx4N, BK=64, T2 XOR
// swizzle both-sides, m201 phase order, single vmcnt(4) per kt at q3.
// ---------------------------------------------------------------------------
__launch_bounds__(512, 2)
__global__ void gemm_mfma256_kernel(const u16* __restrict__ A,   // M x K
                                    const u16* __restrict__ Bt,  // N x K
                                    const float* __restrict__ bias,
                                    float* __restrict__ C,
                                    int M, int N, int K)
{
    __shared__ __align__(16) u16 lds[65536];   // 128 KiB

    // XCD swizzle (bijective: nwg % 8 == 0 at both call sites)
    int nwg = gridDim.x * gridDim.y;
    int bid = blockIdx.y * gridDim.x + blockIdx.x;
    int cpx = nwg >> 3;
    int swz = (bid & 7) * cpx + (bid >> 3);
    int bx = swz % gridDim.x, by = swz / gridDim.x;
    int m0 = by * 256, n0 = bx * 256;

    int tid = threadIdx.x;
    int lane = tid & 63, w = tid >> 6;         // 8 waves
    int lrow = lane & 15, lch = lane >> 4;
    int wm = (w >> 2) * 128;                   // M-half of wave
    int wn = (w & 3) * 64;                     // N-quarter of wave
    int lchx8 = (lch ^ ((lrow >> 1) & 3)) * 8; // swizzled 16B-slot selector

    // staging: wave w owns rows [32w, 32w+32) of each 256-row sub-tile;
    // 2 calls per sub-tile (16 rows each). Source col pre-swizzled so the
    // linear GLDS landing realizes the XOR layout.
    int srow = 32*w + (lane >> 2);             // +16 for second call
    int scol = ((lane & 3) ^ ((lane >> 3) & 3))*8;
    const u16* baseA = A  + (size_t)(m0 + srow)*K + scol;
    const u16* baseB = Bt + (size_t)(n0 + srow)*K + scol;

    // LDS layout (u16 units): buf*32768 + op*16384 + kk*8192 + row*32 + swz(col)
    auto stageA = [&](int kt_, int kk_) {
        u16* dst = lds + (size_t)(((kt_ & 1) << 15) + (kk_ << 13) + (w << 10));
        const u16* src = baseA + (size_t)kt_*64 + (size_t)kk_*32;
        GLDS16(src, dst);
        GLDS16(src + 16*(size_t)K, dst + 512);
    };
    auto stageB = [&](int kt_, int kk_) {
        u16* dst = lds + (size_t)(16384 + ((kt_ & 1) << 15) + (kk_ << 13) + (w << 10));
        const u16* src = baseB + (size_t)kt_*64 + (size_t)kk_*32;
        GLDS16(src, dst);
        GLDS16(src + 16*(size_t)K, dst + 512);
    };

    f32x4 acc[8][4];
    #pragma unroll
    for (int i = 0; i < 8; ++i)
        #pragma unroll
        for (int j = 0; j < 4; ++j)
            acc[i][j] = (f32x4){0.f,0.f,0.f,0.f};

    int NT = K >> 6;   // K-tiles of 64 (12 at both call sites)

    // prologue: kt0 full + kt1.kk0  (12 GLDS instrs/wave outstanding)
    stageA(0, 0); stageB(0, 0);
    stageA(0, 1); stageB(0, 1);
    stageA(1, 0); stageB(1, 0);
    asm volatile("s_waitcnt vmcnt(4)" ::: "memory");   // kt0 landed (own 8)
    __builtin_amdgcn_s_barrier();                      // publish kt0
    asm volatile("" ::: "memory");

    bf16x8 bfr[4];

#define PHASE(mh, kk, STAGE_STMT, LOADB, WAIT_STMT)                             \
    {                                                                           \
        bf16x8 af[4];                                                           \
        _Pragma("unroll")                                                       \
        for (int i = 0; i < 4; ++i)                                             \
            af[i] = *(const bf16x8*)&lds[bsel + ((kk) << 13)                    \
                     + (wm + (mh)*64 + i*16 + lrow)*32 + lchx8];                \
        if (LOADB) {                                                            \
            _Pragma("unroll")                                                   \
            for (int j = 0; j < 4; ++j)                                         \
                bfr[j] = *(const bf16x8*)&lds[bsel + 16384 + ((kk) << 13)       \
                          + (wn + j*16 + lrow)*32 + lchx8];                     \
        }                                                                       \
        STAGE_STMT;                                                             \
        WAIT_STMT;                                                              \
        asm volatile("" ::: "memory");                                          \
        __builtin_amdgcn_s_barrier();                                           \
        __builtin_amdgcn_s_setprio(1);                                          \
        _Pragma("unroll")                                                       \
        for (int i = 0; i < 4; ++i)                                             \
            _Pragma("unroll")                                                   \
            for (int j = 0; j < 4; ++j)                                         \
                acc[(mh)*4 + i][j] = __builtin_amdgcn_mfma_f32_16x16x32_bf16(   \
                    af[i], bfr[j], acc[(mh)*4 + i][j], 0, 0, 0);                \
        __builtin_amdgcn_s_setprio(0);                                          \
        __builtin_amdgcn_s_barrier();                                           \
        asm volatile("" ::: "memory");                                          \
    }

    #pragma unroll 1
    for (int kt = 0; kt < NT; ++kt) {
        const int bsel = (kt & 1) << 15;
        PHASE(0, 0, if (kt + 1 < NT) stageA(kt + 1, 1), 1, )
        PHASE(1, 0, if (kt + 1 < NT) stageB(kt + 1, 1), 0, )
        PHASE(0, 1, if (kt + 2 < NT) stageA(kt + 2, 0), 1, )
        if (kt < NT - 2) {
            PHASE(1, 1, stageB(kt + 2, 0), 0,
                  asm volatile("s_waitcnt vmcnt(4)" ::: "memory"))
        } else {
            PHASE(1, 1, , 0,
                  asm volatile("s_waitcnt vmcnt(0)" ::: "memory"))
        }
    }
#undef PHASE

    // epilogue: bias + fp32 stores
    #pragma unroll
    for (int nt = 0; nt < 4; ++nt) {
        int n = n0 + wn + nt*16 + lrow;
        float bv = bias[n];
        #pragma unroll
        for (int mt = 0; mt < 8; ++mt) {
            int m = m0 + wm + mt*16 + lch*4;
            #pragma unroll
            for (int r = 0; r < 4; ++r)
                C[(size_t)(m + r)*N + n] = acc[mt][nt][r] + bv;
        }
    }
}

// ---------------------------------------------------------------------------
// K3: short conv (width 3, causal) + split; seq=x0*v -> bf16 (B,768,L),
// gate=x1 -> fp32 (B*L,768).
// v2 rolling-window: each thread owns 16 CONSECUTIVE t rows of one d column,
// so u(t-1), u(t-2) roll in registers (3 loads/row instead of 9); taps and
// bias hoisted to 12 registers. Arithmetic order identical to v1.
// ---------------------------------------------------------------------------
__global__ void convprep_kernel(const float* __restrict__ up,
                                const float* __restrict__ conv_W,
                                const float* __restrict__ conv_b,
                                u16* __restrict__ seqbf,
                                float* __restrict__ gate)
{
    __shared__ float sb[64][65];
    int d0 = blockIdx.x * 64;
    int t0 = blockIdx.y * 64;
    int b  = blockIdx.z;
    int tid = threadIdx.x;
    int dcol = tid & 63;
    int tg   = tid >> 6;            // 0..3
    int tb   = t0 + tg*16;          // first t of this thread's run
    int d    = d0 + dcol;

    float w0[3], w1[3], w2[3], cb[3];
    #pragma unroll
    for (int g = 0; g < 3; ++g) {
        int c = d + g*D_MODEL;
        w2[g] = conv_W[c];          // tap for u(t-2)
        w1[g] = conv_W[D3 + c];     // tap for u(t-1)
        w0[g] = conv_W[2*D3 + c];   // tap for u(t)
        cb[g] = conv_b[c];
    }
    float p1[3], p2[3];
    #pragma unroll
    for (int g = 0; g < 3; ++g) {
        size_t rb = ((size_t)b*MAX_LEN + tb)*D3 + d + (size_t)g*D_MODEL;
        p1[g] = (tb >= 1) ? up[rb - D3]   : 0.f;
        p2[g] = (tb >= 2) ? up[rb - 2*D3] : 0.f;
    }
    for (int i = 0; i < 16; ++i) {
        int t = tb + i;
        size_t r = ((size_t)b*MAX_LEN + t)*D3 + d;
        float uc[3];
        #pragma unroll
        for (int g = 0; g < 3; ++g) {
            float u0 = up[r + (size_t)g*D_MODEL];
            uc[g] = w2[g]*p2[g] + w1[g]*p1[g] + w0[g]*u0 + cb[g];
            p2[g] = p1[g];
            p1[g] = u0;
        }
        sb[tg*16 + i][dcol] = uc[0]*uc[2];
        gate[((size_t)b*MAX_LEN + t)*D_MODEL + d] = uc[1];
    }
    __syncthreads();
    #pragma unroll
    for (int i = 0; i < 16; ++i) {
        int idx = tid + 256*i;
        int drow = idx >> 6, tcol = idx & 63;
        seqbf[((size_t)b*D_MODEL + d0 + drow)*MAX_LEN + t0 + tcol] = f2bf(sb[tcol][drow]);
    }
}

// ---------------------------------------------------------------------------
// K4: long causal depthwise conv via block-Toeplitz MFMA (delta-factorized).
// ---------------------------------------------------------------------------
__launch_bounds__(256)
__global__ void longconv_mfma_kernel(const u16* __restrict__ seqbf, // (B,768,L) bf16
                                     const u16* __restrict__ hbf,   // (768,L) bf16
                                     const float* __restrict__ filt_bias,
                                     float* __restrict__ yT)        // (B,768,L) fp32
{
    __shared__ __align__(16) u16 sq[4*4896];   // per-batch swizzled seq, 256-elem zero pad below
    __shared__ __align__(16) u16 hp[4112];     // bf16 h, 16-elem zero pad below
    __shared__ __align__(16) u16 A_s[16*648];  // 16 slabs = rounds 0..15 at segment s

    int d   = blockIdx.x;
    int tid = threadIdx.x;
    int lane = tid & 63, w = tid >> 6;         // w = batch
    int lrow = lane & 15, lch = lane >> 4;

    // stage seq for all 4 batches (9/8 swizzle expansion) + h (shared per d)
    for (int q = tid; q < 4*544; q += 256) {
        int b = q / 544, qq = q - b*544;       // 32 pad quads + 512 data per batch
        int p = b*4896 + ((qq + (qq >> 3)) << 3);
        uint4 o = make_uint4(0u,0u,0u,0u);
        if (qq >= 32) o = *(const uint4*)&seqbf[((size_t)b*D_MODEL + d)*MAX_LEN + (size_t)(qq-32)*8];
        *(uint4*)&sq[p] = o;
    }
    for (int q = tid; q < 514; q += 256) {     // 2 pad quads + 512 data
        uint4 o = make_uint4(0u,0u,0u,0u);
        if (q >= 2) o = *(const uint4*)&hbf[(size_t)d*MAX_LEN + (size_t)(q-2)*8];
        *(uint4*)&hp[q*8] = o;
    }

    f32x4 acc[16];
    #pragma unroll
    for (int g = 0; g < 16; ++g) acc[g] = (f32x4){0.f,0.f,0.f,0.f};

    // slab build: thread -> (round slab_b, row i_b); 16 threads per slab
    int slab_b = tid >> 4;                     // 0..15 = round r
    int i_b    = tid & 15;
    int rot    = (slab_b & 3)*4;               // bank-stagger for the 4 groups/wave
    u32* bld = (u32*)&A_s[slab_b*648 + i_b*40];

    const char* sqb = (const char*)(sq + w*4896);   // per-wave (batch) base
    int Q0 = 30 + 2*lrow + lch;                     // = (240+16lrow+8lch)/8

#define MM(af_, bf_, gi) acc[gi] = __builtin_amdgcn_mfma_f32_16x16x32_bf16(af_, bf_, acc[gi], 0, 0, 0)

    #pragma unroll 1
    for (int s = 0; s < 8; ++s) {
        __syncthreads();   // prior segment's A_s reads done (and staging on s=0)
        {   // build 16 slabs: A(r)[i][k] = hp[32 + 256r + 32s + i - k], k=0..31
            int hbase = 32 + 256*slab_b + 32*s + i_b;
            #pragma unroll
            for (int j = 0; j < 16; ++j) {
                int kk = (j + rot) & 15;
                u16 v0 = hp[hbase - 2*kk];
                u16 v1 = hp[hbase - 2*kk - 1];
                bld[kk] = (u32)v0 | ((u32)v1 << 16);
            }
        }
        __syncthreads();
        bf16x8 aR[16];
        #pragma unroll
        for (int r = 0; r < 16; ++r)
            aR[r] = *(const bf16x8*)&A_s[r*648 + lrow*40 + lch*8];
        int Qs = Q0 - 4*s;                              // >= 2, no negatives
        const char* bp = sqb + (Qs*16 + (Qs >> 3)*16);  // swizzled base
        #pragma unroll
        for (int dlt = 0; dlt < 16; ++dlt) {
            bf16x8 F = *(const bf16x8*)(bp + 576*dlt);  // exact through swizzle
            #pragma unroll
            for (int r = 0; r < 16 - dlt; ++r)
                MM(aR[r], F, r + dlt);
        }
    }
#undef MM

    // epilogue: y = acc + filt_bias[d]*seq ; write fp32 to yT
    float fb = filt_bias[d];
    const u16* sqbu = sq + w*4896;
    float* dsty = yT + ((size_t)w*D_MODEL + d)*MAX_LEN;
    #pragma unroll
    for (int g = 0; g < 16; ++g) {
        int t0 = 256*g + 16*lrow + 4*lch;
        int elem = 256 + t0;                 // multiple of 4; 4 elems in one quad
        int Q = elem >> 3;
        const u16* pv = &sqbu[(((Q + (Q >> 3)) << 3)) | (elem & 7)];
        ushort4 sv = *(const ushort4*)pv;    // 8B aligned
        f4 o;
        o[0] = acc[g][0] + fb*bf2f(sv.x);
        o[1] = acc[g][1] + fb*bf2f(sv.y);
        o[2] = acc[g][2] + fb*bf2f(sv.z);
        o[3] = acc[g][3] + fb*bf2f(sv.w);
        *(f4*)&dsty[t0] = o;
    }
}

// ---------------------------------------------------------------------------
// K5: Afin(bf16)[b*L+t, d] = yT[b,d,t] * gate[b*L+t, d]
// ---------------------------------------------------------------------------
__global__ void gatemul_kernel(const float* __restrict__ yT,
                               const float* __restrict__ gate,
                               u16* __restrict__ Afin)
{
    __shared__ float tb[64][65];
    int d0 = blockIdx.x * 64;
    int t0 = blockIdx.y * 64;
    int b  = blockIdx.z;
    int tid = threadIdx.x;
    #pragma unroll
    for (int i = 0; i < 16; ++i) {
        int idx = tid + 256*i;
        int drow = idx >> 6, tcol = idx & 63;
        tb[drow][tcol] = yT[((size_t)b*D_MODEL + d0 + drow)*MAX_LEN + t0 + tcol];
    }
    __syncthreads();
    #pragma unroll
    for (int i = 0; i < 16; ++i) {
        int idx = tid + 256*i;
        int trow = idx >> 6, dcol = idx & 63;
        size_t r = ((size_t)b*MAX_LEN + t0 + trow)*D_MODEL + d0 + dcol;
        Afin[r] = f2bf(tb[dcol][trow] * gate[r]);
    }
}

// ---------------------------------------------------------------------------
extern "C" void kernel_launch(void* const* d_in, const int* in_sizes, int n_in,
                              void* d_out, int out_size, void* d_ws, size_t ws_size,
                              hipStream_t stream)
{
    (void)in_sizes; (void)n_in; (void)out_size; (void)ws_size;
    const float* u      = (const float*)d_in[0];
    const float* z      = (const float*)d_in[1];
    const float* fin_W  = (const float*)d_in[2];
    const float* fin_b  = (const float*)d_in[3];
    const float* freq   = (const float*)d_in[4];
    const float* mid_W  = (const float*)d_in[5];
    const float* mid_b  = (const float*)d_in[6];
    const float* fout_W = (const float*)d_in[7];
    const float* proj_W = (const float*)d_in[8];
    const float* proj_b = (const float*)d_in[9];
    const float* conv_W = (const float*)d_in[10];
    const float* conv_b = (const float*)d_in[11];
    const float* fbias  = (const float*)d_in[12];
    const float* out_W  = (const float*)d_in[13];
    const float* out_b  = (const float*)d_in[14];
    float* out = (float*)d_out;

    // ws layout (floats), total 65,667,072 f = 262.7 MB:
    float* ws    = (float*)d_ws;
    u16*   hbf   = (u16*)ws;                          // 3,145,728 u16 = 1,572,864 f
    float* up    = ws + 1572864;                      // 37,748,736 f
    float* gate  = up + 37748736;                     // 12,582,912 f
    u16*   seqbf = (u16*)(gate + 12582912);           // 12,582,912 u16 = 6,291,456 f
    u16*   Abf   = (u16*)(gate + 12582912 + 6291456); // 12,582,912 u16 = 6,291,456 f
    u16*   BpT1  = (u16*)(gate + 12582912 + 2*6291456);          // 884,736 f
    u16*   BpT2  = (u16*)(gate + 12582912 + 2*6291456 + 884736); // 294,912 f
    // aliases in regions dead at time of use:
    float* yT    = up;                    // longconv out; up fp32 dead after convprep
    u16*   Afinbf= (u16*)(up + 16777216); // gatemul out; disjoint from yT (12.58M f)
    float* k3buf = gate;                  // 1 MB; gate region dead until convprep

    filter_mlp_kernel<<<MAX_LEN/16, 256, 0, stream>>>(z, fin_W, fin_b, freq,
                                                      mid_W, mid_b, k3buf);
    filter_out_kernel<<<dim3(D_MODEL/128, MAX_LEN/64), 256, 0, stream>>>(
        k3buf, fout_W, hbf);
    cast_bf16_kernel<<<(ROWS*D_MODEL)/(256*8), 256, 0, stream>>>(u, Abf, ROWS*D_MODEL);
    transpose_cast_kernel<<<dim3(D3/64, D_MODEL/64), 256, 0, stream>>>(
        proj_W, BpT1, D_MODEL, D3);
    gemm_mfma256_kernel<<<dim3(D3/256, ROWS/256), 512, 0, stream>>>(
        Abf, BpT1, proj_b, up, ROWS, D3, D_MODEL);
    convprep_kernel<<<dim3(D_MODEL/64, MAX_LEN/64, NBATCH), 256, 0, stream>>>(
        up, conv_W, conv_b, seqbf, gate);
    transpose_cast_kernel<<<dim3(D_MODEL/64, D_MODEL/64), 256, 0, stream>>>(
        out_W, BpT2, D_MODEL, D_MODEL);
    longconv_mfma_kernel<<<D_MODEL, 256, 0, stream>>>(seqbf, hbf, fbias, yT);
    gatemul_kernel<<<dim3(D_MODEL/64, MAX_LEN/64, NBATCH), 256, 0, stream>>>(
        yT, gate, Afinbf);
    gemm_mfma256_kernel<<<dim3(D_MODEL/256, ROWS/256), 512, 0, stream>>>(
        Afinbf, BpT2, out_b, out, ROWS, D_MODEL, D_MODEL);
}